// Round 1
// baseline (7104.137 us; speedup 1.0000x reference)
//
#include <hip/hip_runtime.h>

// RLIF forward: T=256 serial steps; per step z = y @ Wr.T (+tx+br), LIF update.
// Round 0: correctness-first fp32 baseline, one kernel launch per timestep.

#define T_STEPS 256
#define BATCH   128
#define NNEUR   1024
#define DECAY_F 0.2f
#define THRESH  0.3f

#define BTILE 16            // batches per workgroup
#define ITILE 32            // output neurons per workgroup
#define KC    128           // K-chunk staged in LDS
#define WT_STRIDE (KC + 1)  // +1 pad: conflict-free lane-varying row reads

__global__ __launch_bounds__(256)
void rlif_step(const float* __restrict__ tx_t,    // [B][N] input slice for step t
               const float* __restrict__ y_prev,  // [B][N] spikes from t-1 (null at t=0)
               const float* __restrict__ Wr,      // [N][N] row-major
               const float* __restrict__ br,      // [N]
               float* __restrict__ v,             // [B][N] membrane state (ws)
               float* __restrict__ out_t,         // [B][N] spikes for step t
               int t)
{
    __shared__ float yt[BTILE * KC];
    __shared__ float wt[ITILE * WT_STRIDE];

    const int tid = threadIdx.x;
    const int bb  = blockIdx.x >> 5;   // 8 batch-blocks
    const int ib  = blockIdx.x & 31;   // 32 neuron-blocks
    const int il  = tid & 31;          // neuron within tile
    const int sub = tid >> 5;          // 0..7 -> handles 2 batches
    const int i   = ib * ITILE + il;
    const int b0  = bb * BTILE + sub * 2;
    const int b1  = b0 + 1;

    float acc0 = 0.f, acc1 = 0.f;

    if (t > 0) {
        for (int jc = 0; jc < NNEUR; jc += KC) {
            // stage y tile [BTILE][KC]
            for (int e = tid; e < BTILE * KC; e += 256) {
                int r = e >> 7, c = e & (KC - 1);
                yt[r * KC + c] = y_prev[(size_t)(bb * BTILE + r) * NNEUR + jc + c];
            }
            // stage Wr tile [ITILE][KC] (rows i, contiguous j) with +1 pad
            for (int e = tid; e < ITILE * KC; e += 256) {
                int r = e >> 7, c = e & (KC - 1);
                wt[r * WT_STRIDE + c] = Wr[(size_t)(ib * ITILE + r) * NNEUR + jc + c];
            }
            __syncthreads();

            const float* yr0 = &yt[(2 * sub) * KC];
            const float* yr1 = &yt[(2 * sub + 1) * KC];
            const float* wr  = &wt[il * WT_STRIDE];
            #pragma unroll 8
            for (int kk = 0; kk < KC; ++kk) {
                float w = wr[kk];
                acc0 += yr0[kk] * w;
                acc1 += yr1[kk] * w;
            }
            __syncthreads();
        }
    }

    // LIF update (mirror reference op order: (tx + rec) + br)
    const float brv = br[i];
    float x0 = (tx_t[(size_t)b0 * NNEUR + i] + acc0) + brv;
    float x1 = (tx_t[(size_t)b1 * NNEUR + i] + acc1) + brv;
    float v0 = (t > 0) ? (DECAY_F * v[(size_t)b0 * NNEUR + i] + x0) : x0;
    float v1 = (t > 0) ? (DECAY_F * v[(size_t)b1 * NNEUR + i] + x1) : x1;
    float s0 = (v0 > THRESH) ? 1.f : 0.f;
    float s1 = (v1 > THRESH) ? 1.f : 0.f;
    v[(size_t)b0 * NNEUR + i] = (v0 > THRESH) ? 0.f : v0;  // hard reset to rest=0
    v[(size_t)b1 * NNEUR + i] = (v1 > THRESH) ? 0.f : v1;
    out_t[(size_t)b0 * NNEUR + i] = s0;
    out_t[(size_t)b1 * NNEUR + i] = s1;
}

extern "C" void kernel_launch(void* const* d_in, const int* in_sizes, int n_in,
                              void* d_out, int out_size, void* d_ws, size_t ws_size,
                              hipStream_t stream)
{
    const float* tx = (const float*)d_in[0];  // [T][B][N]
    const float* Wr = (const float*)d_in[1];  // [N][N]
    const float* br = (const float*)d_in[2];  // [N]
    float* out = (float*)d_out;               // [T][B][N] spikes
    float* v   = (float*)d_ws;                // [B][N] membrane state

    const size_t step = (size_t)BATCH * NNEUR;
    for (int t = 0; t < T_STEPS; ++t) {
        const float* ypv = (t == 0) ? nullptr : (out + (size_t)(t - 1) * step);
        rlif_step<<<dim3(256), dim3(256), 0, stream>>>(
            tx + (size_t)t * step, ypv, Wr, br, v, out + (size_t)t * step, t);
    }
}